// Round 1
// baseline (43.925 us; speedup 1.0000x reference)
//
#include <hip/hip_runtime.h>

#define WIN_SIZE   400
#define WIN_SHIFT  160
#define BATCH      32
#define T_LEN      480000
#define NFRAMES    2998           // (480000-400)/160 + 1
#define FTILE      64
#define NTILES     47             // ceil(2998/64)
#define SAMPLES    ((FTILE-1)*WIN_SHIFT + WIN_SIZE)   // 10480
#define SAMPLES_PAD 10496

// XOR-swizzle: stride-160 (== 5*32) reads would be a 32-way bank conflict.
// bank(swz(f*160+w)) = (w&31) ^ ((5f + (w>>5)) & 31); 5 coprime 32 -> 2-way
// over 64 lanes (free, m136). Staging writes: per-32-block constant XOR =
// bank permutation -> conflict-free.
__device__ __forceinline__ int swz(int a) { return a ^ ((a >> 5) & 31); }

__global__ __launch_bounds__(256) void window_frame_kernel(
    const float* __restrict__ x, const float* __restrict__ window,
    float* __restrict__ out)
{
    __shared__ float lx[SAMPLES_PAD];
    __shared__ float lw[WIN_SIZE];

    const int tile = blockIdx.x;          // frame tile
    const int b    = blockIdx.y;          // batch
    const int f0   = tile * FTILE;
    const long base = (long)b * T_LEN + (long)f0 * WIN_SHIFT;
    const int avail = T_LEN - f0 * WIN_SHIFT;            // multiple of 16
    const int need  = min(SAMPLES, avail);               // floats to stage
    const int need4 = need >> 2;                         // float4 count (need%4==0)

    const int tid = threadIdx.x;

    // stage window (broadcast-read later, conflict-free)
    for (int i = tid; i < WIN_SIZE; i += 256) lw[i] = window[i];

    // stage x tile: coalesced float4 global loads -> swizzled scalar LDS writes
    const float4* __restrict__ xg = (const float4*)(x + base);
    for (int i4 = tid; i4 < need4; i4 += 256) {
        float4 v = xg[i4];
        int a = i4 << 2;
        lx[swz(a + 0)] = v.x;
        lx[swz(a + 1)] = v.y;
        lx[swz(a + 2)] = v.z;
        lx[swz(a + 3)] = v.w;
    }
    __syncthreads();

    const int lane = tid & 63;
    const int wid  = tid >> 6;
    const int f    = f0 + lane;
    const bool ok  = f < NFRAMES;        // tail tile: frames 2944..2997 only
    float* __restrict__ op = out + (long)b * WIN_SIZE * NFRAMES + f;
    const int abase = lane * WIN_SHIFT;

    // each wave owns w = wid, wid+4, ... (100 iters); lane = frame offset.
    // store: 64 consecutive floats per wave = 256 B coalesced.
    #pragma unroll 4
    for (int w = wid; w < WIN_SIZE; w += 4) {
        float v = lx[swz(abase + w)] * lw[w];
        if (ok) op[(long)w * NFRAMES] = v;
    }
}

extern "C" void kernel_launch(void* const* d_in, const int* in_sizes, int n_in,
                              void* d_out, int out_size, void* d_ws, size_t ws_size,
                              hipStream_t stream) {
    const float* x      = (const float*)d_in[0];
    const float* window = (const float*)d_in[1];
    // d_in[2] = win_shift scalar (160) — compile-time constant here
    float* out = (float*)d_out;

    dim3 grid(NTILES, BATCH);
    window_frame_kernel<<<grid, 256, 0, stream>>>(x, window, out);
}

// Round 2
// 39.663 us; speedup vs baseline: 1.1075x; 1.1075x over previous
//
#include <hip/hip_runtime.h>

#define WIN_SIZE   400
#define WIN_SHIFT  160
#define BATCH      32
#define T_LEN      480000
#define NFRAMES    2998           // (480000-400)/160 + 1
#define FTILE      64
#define NTILES     47             // ceil(2998/64)
#define NBLOCKS    (NTILES * BATCH)        // 1504 = 8 * 188
#define PER_XCD    (NBLOCKS / 8)           // 188 = 4 batches * 47 tiles
#define SAMPLES    ((FTILE-1)*WIN_SHIFT + WIN_SIZE)   // 10480
#define SAMPLES_PAD 10496

// XOR-swizzle: stride-160 (== 5*32) reads would be a 32-way bank conflict.
// bank(swz(f*160+w)) = (w&31) ^ ((5f + (w>>5)) & 31); 5 coprime 32 -> 2-way
// over 64 lanes (free, m136). Staging writes: per-32-block constant XOR =
// bank permutation -> conflict-free.
__device__ __forceinline__ int swz(int a) { return a ^ ((a >> 5) & 31); }

__global__ __launch_bounds__(256) void window_frame_kernel(
    const float* __restrict__ x, const float* __restrict__ window,
    float* __restrict__ out)
{
    __shared__ float lx[SAMPLES_PAD];
    __shared__ float lw[WIN_SIZE];

    // XCD-aware bijective swizzle: HW dispatches flat id i to XCD i%8.
    // Map so each XCD owns 188 CONSECUTIVE (b,tile) ids = 4 whole batches ->
    // tile-boundary 64B lines are merged within one L2 (never split cross-XCD).
    const int flat  = blockIdx.x;
    const int lin   = (flat & 7) * PER_XCD + (flat >> 3);
    const int b     = lin / NTILES;
    const int tile  = lin % NTILES;

    const int f0   = tile * FTILE;
    const long base = (long)b * T_LEN + (long)f0 * WIN_SHIFT;
    const int avail = T_LEN - f0 * WIN_SHIFT;            // multiple of 16
    const int need  = min(SAMPLES, avail);               // floats to stage
    const int need4 = need >> 2;                         // float4 count (need%4==0)

    const int tid = threadIdx.x;

    // stage window (broadcast-read later, conflict-free)
    for (int i = tid; i < WIN_SIZE; i += 256) lw[i] = window[i];

    // stage x tile: coalesced float4 global loads -> swizzled scalar LDS writes
    const float4* __restrict__ xg = (const float4*)(x + base);
    for (int i4 = tid; i4 < need4; i4 += 256) {
        float4 v = xg[i4];
        int a = i4 << 2;
        lx[swz(a + 0)] = v.x;
        lx[swz(a + 1)] = v.y;
        lx[swz(a + 2)] = v.z;
        lx[swz(a + 3)] = v.w;
    }
    __syncthreads();

    const int lane = tid & 63;
    const int wid  = tid >> 6;
    const int f    = f0 + lane;
    const bool ok  = f < NFRAMES;        // tail tile: frames 2944..2997 only
    float* __restrict__ op = out + (long)b * WIN_SIZE * NFRAMES + f;
    const int abase = lane * WIN_SHIFT;

    // each wave owns w = wid, wid+4, ... (100 iters); lane = frame offset.
    // store: 64 consecutive floats per wave = 256 B coalesced.
    #pragma unroll 4
    for (int w = wid; w < WIN_SIZE; w += 4) {
        float v = lx[swz(abase + w)] * lw[w];
        if (ok) op[(long)w * NFRAMES] = v;
    }
}

extern "C" void kernel_launch(void* const* d_in, const int* in_sizes, int n_in,
                              void* d_out, int out_size, void* d_ws, size_t ws_size,
                              hipStream_t stream) {
    const float* x      = (const float*)d_in[0];
    const float* window = (const float*)d_in[1];
    // d_in[2] = win_shift scalar (160) — compile-time constant here
    float* out = (float*)d_out;

    window_frame_kernel<<<NBLOCKS, 256, 0, stream>>>(x, window, out);
}